// Round 2
// baseline (19842.421 us; speedup 1.0000x reference)
//
#include <hip/hip_runtime.h>
#include <hip/hip_bf16.h>

typedef __hip_bfloat16 bf16;
typedef unsigned char u8;
#define DI __device__ __forceinline__

union BF8 { int4 v; bf16 h[8]; };
union BF4 { unsigned long long u; bf16 h[4]; };

// ws layout (bytes), total 234,913,792 (~224 MiB):
// concatA bf16 [128][256][1024]  :           0 ..  67,108,864   (sections 0,1: +residual)
// concatB u8   [128][256][1024]  :  67,108,864 .. 100,663,296   (sections 2,3: softmax out, x256 fixed pt)
// x3 bf16 [128][128][1024]       : 100,663,296 .. 134,217,728
// x5 bf16                        : 134,217,728 .. 167,772,160
// x7 bf16                        : 167,772,160 .. 201,326,592
// x1 bf16                        : 201,326,592 .. 234,881,024
// parts f32 (4 x 2048)           : 234,881,024 .. 234,913,792
// projchunk bf16 [6][128][64][1024] = 100,663,296 B, OVERLAPS x3..x1 region
//   (safe: proj/attn chunks complete before any conv launches; stream-ordered)

// ---------------------------------------------------------------- projections (64-ch chunk)
__global__ __launch_bounds__(256) void proj_chunk_kernel(
    const float* __restrict__ st, const float* __restrict__ phy,
    const float* __restrict__ w0, const float* __restrict__ b0,
    const float* __restrict__ w1, const float* __restrict__ b1,
    const float* __restrict__ w2, const float* __restrict__ b2,
    const float* __restrict__ w3, const float* __restrict__ b3,
    const float* __restrict__ w4, const float* __restrict__ b4,
    const float* __restrict__ w5, const float* __restrict__ b5,
    bf16* __restrict__ pc, int cb)
{
  __shared__ __align__(16) bf16 Xs[128][128];   // [in_ch][pos] of this pos-chunk
  __shared__ __align__(16) bf16 Ws[128][64];    // [in_ch][out_ch(local)]
  const int pt = blockIdx.x, b = blockIdx.y;
  const int tid = threadIdx.x;
  const int c0 = (tid >> 4) * 4;      // local out-ch 0..60
  const int p0 = (tid & 15) * 8;      // pos-in-chunk 0..120

  #pragma unroll
  for (int mat = 0; mat < 6; ++mat) {
    const float* Wm; const float* Bm; const float* X;
    switch (mat) {
      case 0: Wm = w0; Bm = b0; X = st;  break;
      case 1: Wm = w1; Bm = b1; X = st;  break;
      case 2: Wm = w2; Bm = b2; X = st;  break;
      case 3: Wm = w3; Bm = b3; X = phy; break;
      case 4: Wm = w4; Bm = b4; X = phy; break;
      default:Wm = w5; Bm = b5; X = phy; break;
    }
    __syncthreads();   // previous compute done; Xs/Ws safe to overwrite
    if (mat == 0 || mat == 3) {
      for (int e = tid; e < 128 * 128; e += 256) {
        int i = e >> 7, p = e & 127;
        Xs[i][p] = __float2bfloat16(X[((size_t)b * 128 + i) * 1024 + pt * 128 + p]);
      }
    }
    for (int e = tid; e < 64 * 128; e += 256) {
      int c = e >> 7, i = e & 127;
      Ws[i][c] = __float2bfloat16(Wm[(cb + c) * 128 + i]);
    }
    __syncthreads();

    float acc[4][8];
    #pragma unroll
    for (int a = 0; a < 4; ++a)
      #pragma unroll
      for (int d = 0; d < 8; ++d) acc[a][d] = 0.f;

    #pragma unroll 2
    for (int i = 0; i < 128; ++i) {
      BF4 wv; wv.u = *(const unsigned long long*)&Ws[i][c0];
      BF8 xv; xv.v = *(const int4*)&Xs[i][p0];
      float wf[4], xf[8];
      #pragma unroll
      for (int j = 0; j < 4; ++j) wf[j] = __bfloat162float(wv.h[j]);
      #pragma unroll
      for (int j = 0; j < 8; ++j) xf[j] = __bfloat162float(xv.h[j]);
      #pragma unroll
      for (int cc = 0; cc < 4; ++cc)
        #pragma unroll
        for (int pp = 0; pp < 8; ++pp)
          acc[cc][pp] = fmaf(wf[cc], xf[pp], acc[cc][pp]);
    }
    #pragma unroll
    for (int cc = 0; cc < 4; ++cc) {
      float bias = Bm[cb + c0 + cc];
      BF8 pk;
      #pragma unroll
      for (int pp = 0; pp < 8; ++pp) pk.h[pp] = __float2bfloat16(acc[cc][pp] + bias);
      *(int4*)&pc[(((size_t)mat * 128 + b) * 64 + c0 + cc) * 1024 + pt * 128 + p0] = pk.v;
    }
  }
}

// ---------------------------------------------------------------- attention helpers
DI void mm32(const float* A, int sa, const float* Bm, int sb,
             float acc[4][4], int r0, int c0)
{
  #pragma unroll 4
  for (int w = 0; w < 32; ++w) {
    float qv[4], kv[4];
    *(float4*)qv = *(const float4*)(A + w * sa + r0);
    *(float4*)kv = *(const float4*)(Bm + w * sb + c0);
    #pragma unroll
    for (int i = 0; i < 4; ++i)
      #pragma unroll
      for (int j = 0; j < 4; ++j)
        acc[i][j] = fmaf(qv[i], kv[j], acc[i][j]);
  }
}

DI void softmax4(float acc[4][4])
{
  #pragma unroll
  for (int i = 0; i < 4; ++i) {
    float m = fmaxf(fmaxf(acc[i][0], acc[i][1]), fmaxf(acc[i][2], acc[i][3]));
    m = fmaxf(m, __shfl_xor(m, 1));
    m = fmaxf(m, __shfl_xor(m, 2));
    m = fmaxf(m, __shfl_xor(m, 4));
    float s = 0.f;
    #pragma unroll
    for (int j = 0; j < 4; ++j) { acc[i][j] = __expf(acc[i][j] - m); s += acc[i][j]; }
    s += __shfl_xor(s, 1); s += __shfl_xor(s, 2); s += __shfl_xor(s, 4);
    float rs = 1.0f / s;
    #pragma unroll
    for (int j = 0; j < 4; ++j) acc[i][j] *= rs;
  }
}

template<bool U8OUT>
DI void attn_one(const float* Qt, const float* K, const float* V, float (*At)[36],
                 const float* resid, void* outp, int r0, int c0)
{
  float acc[4][4] = {};
  mm32(Qt, 36, K, 32, acc, r0, c0);
  softmax4(acc);
  __syncthreads();
  #pragma unroll
  for (int j = 0; j < 4; ++j)
    *(float4*)&At[c0 + j][r0] = make_float4(acc[0][j], acc[1][j], acc[2][j], acc[3][j]);
  __syncthreads();
  float o[4][4] = {};
  mm32(&At[0][0], 36, V, 32, o, r0, c0);
  softmax4(o);
  if constexpr (!U8OUT) {
    bf16* op = (bf16*)outp;
    if (resid) {
      #pragma unroll
      for (int i = 0; i < 4; ++i) {
        float4 rv = *(const float4*)&resid[(r0 + i) * 32 + c0];
        o[i][0] += rv.x; o[i][1] += rv.y; o[i][2] += rv.z; o[i][3] += rv.w;
      }
    }
    #pragma unroll
    for (int i = 0; i < 4; ++i) {
      BF4 pk;
      #pragma unroll
      for (int j = 0; j < 4; ++j) pk.h[j] = __float2bfloat16(o[i][j]);
      *(unsigned long long*)&op[(r0 + i) * 32 + c0] = pk.u;
    }
  } else {
    u8* op = (u8*)outp;
    #pragma unroll
    for (int i = 0; i < 4; ++i) {
      unsigned pk = 0;
      #pragma unroll
      for (int j = 0; j < 4; ++j) {
        unsigned bv = (unsigned)fminf(o[i][j] * 256.f + 0.5f, 255.f);
        pk |= bv << (8 * j);
      }
      *(unsigned*)&op[(r0 + i) * 32 + c0] = pk;
    }
  }
}

// ---------------------------------------------------------------- attention (64-ch chunk)
__global__ __launch_bounds__(64) void attn_chunk_kernel(
    const bf16* __restrict__ pc,
    const float* __restrict__ st, const float* __restrict__ phy,
    bf16* __restrict__ cA, u8* __restrict__ cB, int cb)
{
  __shared__ __align__(16) float Qst[32][36], Qphy[32][36];
  __shared__ __align__(16) float Kst[32][32], Kphy[32][32];
  __shared__ __align__(16) float Vst[32][32], Vphy[32][32];
  __shared__ __align__(16) float At[32][36];
  const int cl = blockIdx.x, b = blockIdx.y;
  const int c = cb + cl;
  const int lane = threadIdx.x;
  const size_t mstride = (size_t)128 * 64 * 1024;
  const bf16* p0 = pc + ((size_t)b * 64 + cl) * 1024;
  const size_t bc = ((size_t)b * 128 + c) * 1024;

  for (int e = lane; e < 1024; e += 64) {
    int h = e >> 5, w = e & 31;
    Qst[w][h]  = __bfloat162float(p0[e]);
    Kst[h][w]  = __bfloat162float(p0[mstride + e]);
    Vst[h][w]  = __bfloat162float(p0[2 * mstride + e]);
    Qphy[w][h] = __bfloat162float(p0[3 * mstride + e]);
    Kphy[h][w] = __bfloat162float(p0[4 * mstride + e]);
    Vphy[h][w] = __bfloat162float(p0[5 * mstride + e]);
  }
  __syncthreads();
  const int r0 = (lane >> 3) * 4, c0 = (lane & 7) * 4;
  bf16* aA = cA + (size_t)b * 256 * 1024 + (size_t)c * 1024;
  u8*   aB = cB + (size_t)b * 256 * 1024 + (size_t)c * 1024;

  attn_one<false>(&Qst[0][0],  &Kst[0][0],  &Vst[0][0],  At, st + bc,  aA,               r0, c0);
  attn_one<false>(&Qphy[0][0], &Kphy[0][0], &Vphy[0][0], At, phy + bc, aA + 128 * 1024,  r0, c0);
  attn_one<true >(&Qphy[0][0], &Kst[0][0],  &Vst[0][0],  At, nullptr,  aB,               r0, c0);
  attn_one<true >(&Qst[0][0],  &Kphy[0][0], &Vphy[0][0], At, nullptr,  aB + 128 * 1024,  r0, c0);
}

// ---------------------------------------------------------------- direct conv k=3/5/7
template<int KS>
__global__ __launch_bounds__(256) void conv_kernel(
    const bf16* __restrict__ cA, const u8* __restrict__ cB,
    const float* __restrict__ w,
    bf16* __restrict__ xout, float* __restrict__ partials)
{
  constexpr int H0 = KS / 2;
  constexpr int TR = 4 + 2 * H0;
  constexpr int TC = 32 + 2 * H0;
  constexpr int TCP = (TC + 3) & ~3;
  __shared__ float tile[4][TR][TCP];
  __shared__ float rs[256], rq[256];
  const int rg = blockIdx.x, b = blockIdx.y;
  const int tid = threadIdx.x;
  const int oc = tid & 127, rh = tid >> 7;
  const int row_lo = rh * 2;

  float acc0[32], acc1[32];
  #pragma unroll
  for (int x = 0; x < 32; ++x) { acc0[x] = 0.f; acc1[x] = 0.f; }

  for (int ic0 = 0; ic0 < 512; ic0 += 4) {
    __syncthreads();
    for (int e = tid; e < 4 * TR * TCP; e += 256) {
      int ci = e / (TR * TCP); int rem = e - ci * (TR * TCP);
      int ry = rem / TCP; int cx = rem - ry * TCP;
      int grow = rg * 4 - H0 + ry, gcol = cx - H0;
      float v = 0.f;
      if (grow >= 0 && grow < 32 && gcol >= 0 && gcol < 32) {
        int ic = ic0 + ci;
        size_t gidx = ((size_t)b * 256 + (ic & 255)) * 1024 + grow * 32 + gcol;
        v = (ic < 256) ? __bfloat162float(cA[gidx]) : (float)cB[gidx] * 0.00390625f;
      }
      tile[ci][ry][cx] = v;
    }
    __syncthreads();
    const float* wb = w + ((size_t)oc * 512 + ic0) * (KS * KS);
    #pragma unroll 1
    for (int ci = 0; ci < 4; ++ci) {
      #pragma unroll 1
      for (int ky = 0; ky < KS; ++ky) {
        float wk[KS];
        #pragma unroll
        for (int kx = 0; kx < KS; ++kx) wk[kx] = wb[ci * KS * KS + ky * KS + kx];
        {
          float seg[TC];
          #pragma unroll
          for (int x = 0; x < TC; ++x) seg[x] = tile[ci][row_lo + ky][x];
          #pragma unroll
          for (int kx = 0; kx < KS; ++kx)
            #pragma unroll
            for (int x = 0; x < 32; ++x)
              acc0[x] = fmaf(wk[kx], seg[x + kx], acc0[x]);
        }
        {
          float seg[TC];
          #pragma unroll
          for (int x = 0; x < TC; ++x) seg[x] = tile[ci][row_lo + 1 + ky][x];
          #pragma unroll
          for (int kx = 0; kx < KS; ++kx)
            #pragma unroll
            for (int x = 0; x < 32; ++x)
              acc1[x] = fmaf(wk[kx], seg[x + kx], acc1[x]);
        }
      }
    }
  }

  const int orow = rg * 4 + rh * 2;
  size_t obase = ((size_t)b * 128 + oc) * 1024 + (size_t)orow * 32;
  #pragma unroll
  for (int xq = 0; xq < 8; ++xq) {
    BF4 pk;
    #pragma unroll
    for (int j = 0; j < 4; ++j) pk.h[j] = __float2bfloat16(acc0[xq * 4 + j]);
    *(unsigned long long*)&xout[obase + xq * 4] = pk.u;
  }
  #pragma unroll
  for (int xq = 0; xq < 8; ++xq) {
    BF4 pk;
    #pragma unroll
    for (int j = 0; j < 4; ++j) pk.h[j] = __float2bfloat16(acc1[xq * 4 + j]);
    *(unsigned long long*)&xout[obase + 32 + xq * 4] = pk.u;
  }
  float lsum = 0.f, lsq = 0.f;
  #pragma unroll
  for (int x = 0; x < 32; ++x) {
    lsum += acc0[x] + acc1[x];
    lsq += acc0[x] * acc0[x] + acc1[x] * acc1[x];
  }
  rs[tid] = lsum; rq[tid] = lsq;
  __syncthreads();
  for (int s = 128; s > 0; s >>= 1) {
    if (tid < s) { rs[tid] += rs[tid + s]; rq[tid] += rq[tid + s]; }
    __syncthreads();
  }
  if (tid == 0) {
    partials[(size_t)(b * 8 + rg) * 2]     = rs[0];
    partials[(size_t)(b * 8 + rg) * 2 + 1] = rq[0];
  }
}

// ---------------------------------------------------------------- conv k=1 (GEMM) + b1
__global__ __launch_bounds__(256) void conv1_kernel(
    const bf16* __restrict__ cA, const u8* __restrict__ cB,
    const float* __restrict__ w1, const float* __restrict__ b1,
    bf16* __restrict__ xout, float* __restrict__ partials)
{
  __shared__ __align__(16) bf16 Xs[64][128];
  __shared__ __align__(16) bf16 Ws[64][136];
  __shared__ float rs[256], rq[256];
  const int pt = blockIdx.x, b = blockIdx.y;
  const int p0 = pt * 128, tid = threadIdx.x;
  const int c0 = (tid >> 4) * 8, q0 = (tid & 15) * 8;
  float acc[8][8] = {};

  for (int ic0 = 0; ic0 < 512; ic0 += 64) {
    __syncthreads();
    for (int e = tid; e < 64 * 128; e += 256) {
      int i = e >> 7, p = e & 127;
      int ic = ic0 + i;
      size_t gidx = ((size_t)b * 256 + (ic & 255)) * 1024 + p0 + p;
      Xs[i][p] = (ic < 256) ? cA[gidx]
                            : __float2bfloat16((float)cB[gidx] * 0.00390625f);
    }
    for (int e = tid; e < 64 * 128; e += 256) {
      int i = e & 63, cix = e >> 6;
      Ws[i][cix] = __float2bfloat16(w1[(size_t)cix * 512 + ic0 + i]);
    }
    __syncthreads();
    for (int i = 0; i < 64; ++i) {
      BF8 wvv, xvv;
      wvv.v = *(const int4*)&Ws[i][c0];
      xvv.v = *(const int4*)&Xs[i][q0];
      float wf[8], xf[8];
      #pragma unroll
      for (int j = 0; j < 8; ++j) {
        wf[j] = __bfloat162float(wvv.h[j]);
        xf[j] = __bfloat162float(xvv.h[j]);
      }
      #pragma unroll
      for (int cc = 0; cc < 8; ++cc)
        #pragma unroll
        for (int pp = 0; pp < 8; ++pp)
          acc[cc][pp] = fmaf(wf[cc], xf[pp], acc[cc][pp]);
    }
  }
  float lsum = 0.f, lsq = 0.f;
  #pragma unroll
  for (int cc = 0; cc < 8; ++cc) {
    float bias = b1[c0 + cc];
    BF8 pk;
    #pragma unroll
    for (int pp = 0; pp < 8; ++pp) {
      float v = acc[cc][pp] + bias;
      pk.h[pp] = __float2bfloat16(v);
      lsum += v; lsq += v * v;
    }
    *(int4*)&xout[((size_t)b * 128 + c0 + cc) * 1024 + p0 + q0] = pk.v;
  }
  rs[tid] = lsum; rq[tid] = lsq;
  __syncthreads();
  for (int s = 128; s > 0; s >>= 1) {
    if (tid < s) { rs[tid] += rs[tid + s]; rq[tid] += rq[tid + s]; }
    __syncthreads();
  }
  if (tid == 0) {
    partials[(size_t)(b * 8 + pt) * 2]     = rs[0];
    partials[(size_t)(b * 8 + pt) * 2 + 1] = rq[0];
  }
}

// ---------------------------------------------------------------- LN + combine
__global__ __launch_bounds__(256) void final_kernel(
    const bf16* __restrict__ x3, const bf16* __restrict__ x5,
    const bf16* __restrict__ x7, const bf16* __restrict__ x1c,
    const float* __restrict__ p3, const float* __restrict__ p5,
    const float* __restrict__ p7, const float* __restrict__ p1,
    const float* __restrict__ g3, const float* __restrict__ be3,
    const float* __restrict__ g5, const float* __restrict__ be5,
    const float* __restrict__ g7, const float* __restrict__ be7,
    const float* __restrict__ g1, const float* __restrict__ be1,
    float* __restrict__ out)
{
  const int blk = blockIdx.x, b = blockIdx.y, tid = threadIdx.x;
  float s3 = 0, q3 = 0, s5 = 0, q5 = 0, s7 = 0, q7 = 0, s1 = 0, q1 = 0;
  #pragma unroll
  for (int i = 0; i < 8; ++i) {
    int o = (b * 8 + i) * 2;
    s3 += p3[o]; q3 += p3[o + 1];
    s5 += p5[o]; q5 += p5[o + 1];
    s7 += p7[o]; q7 += p7[o + 1];
    s1 += p1[o]; q1 += p1[o + 1];
  }
  const float inv = 1.0f / 131072.0f;
  float mu3 = s3 * inv, r3 = rsqrtf(fmaxf(q3 * inv - mu3 * mu3, 0.f) + 1e-5f);
  float mu5 = s5 * inv, r5 = rsqrtf(fmaxf(q5 * inv - mu5 * mu5, 0.f) + 1e-5f);
  float mu7 = s7 * inv, r7 = rsqrtf(fmaxf(q7 * inv - mu7 * mu7, 0.f) + 1e-5f);
  float mu1 = s1 * inv, r1 = rsqrtf(fmaxf(q1 * inv - mu1 * mu1, 0.f) + 1e-5f);
  const size_t bb = (size_t)b * 131072;
  for (int it = 0; it < 8; ++it) {
    int e0 = (it * 2048 + blk * 256 + tid) * 8;
    BF8 a3, a5, a7, a1;
    a3.v = *(const int4*)&x3[bb + e0];
    a5.v = *(const int4*)&x5[bb + e0];
    a7.v = *(const int4*)&x7[bb + e0];
    a1.v = *(const int4*)&x1c[bb + e0];
    float G3[8], B3[8], G5[8], B5[8], G7[8], B7[8], G1[8], B1[8];
    *(float4*)&G3[0] = *(const float4*)&g3[e0];  *(float4*)&G3[4] = *(const float4*)&g3[e0 + 4];
    *(float4*)&B3[0] = *(const float4*)&be3[e0]; *(float4*)&B3[4] = *(const float4*)&be3[e0 + 4];
    *(float4*)&G5[0] = *(const float4*)&g5[e0];  *(float4*)&G5[4] = *(const float4*)&g5[e0 + 4];
    *(float4*)&B5[0] = *(const float4*)&be5[e0]; *(float4*)&B5[4] = *(const float4*)&be5[e0 + 4];
    *(float4*)&G7[0] = *(const float4*)&g7[e0];  *(float4*)&G7[4] = *(const float4*)&g7[e0 + 4];
    *(float4*)&B7[0] = *(const float4*)&be7[e0]; *(float4*)&B7[4] = *(const float4*)&be7[e0 + 4];
    *(float4*)&G1[0] = *(const float4*)&g1[e0];  *(float4*)&G1[4] = *(const float4*)&g1[e0 + 4];
    *(float4*)&B1[0] = *(const float4*)&be1[e0]; *(float4*)&B1[4] = *(const float4*)&be1[e0 + 4];
    float res[8];
    #pragma unroll
    for (int j = 0; j < 8; ++j) {
      float v3 = (__bfloat162float(a3.h[j]) - mu3) * r3 * G3[j] + B3[j];
      float v5 = (__bfloat162float(a5.h[j]) - mu5) * r5 * G5[j] + B5[j];
      float v7 = (__bfloat162float(a7.h[j]) - mu7) * r7 * G7[j] + B7[j];
      float m = (v3 + v5 + v7) * (1.0f / 3.0f);
      float sg = 1.0f / (1.0f + __expf(-m));
      float v1 = (__bfloat162float(a1.h[j]) - mu1) * r1 * G1[j] + B1[j];
      res[j] = sg + v1;
    }
    *(float4*)&out[bb + e0]     = make_float4(res[0], res[1], res[2], res[3]);
    *(float4*)&out[bb + e0 + 4] = make_float4(res[4], res[5], res[6], res[7]);
  }
}

// ---------------------------------------------------------------- launch
extern "C" void kernel_launch(void* const* d_in, const int* in_sizes, int n_in,
                              void* d_out, int out_size, void* d_ws, size_t ws_size,
                              hipStream_t stream)
{
  (void)in_sizes; (void)n_in; (void)out_size; (void)ws_size;
  const float* st     = (const float*)d_in[0];
  const float* phy    = (const float*)d_in[1];
  const float* wq_st  = (const float*)d_in[2];
  const float* bq_st  = (const float*)d_in[3];
  const float* wk_st  = (const float*)d_in[4];
  const float* bk_st  = (const float*)d_in[5];
  const float* wv_st  = (const float*)d_in[6];
  const float* bv_st  = (const float*)d_in[7];
  const float* wq_phy = (const float*)d_in[8];
  const float* bq_phy = (const float*)d_in[9];
  const float* wk_phy = (const float*)d_in[10];
  const float* bk_phy = (const float*)d_in[11];
  const float* wv_phy = (const float*)d_in[12];
  const float* bv_phy = (const float*)d_in[13];
  const float* w3  = (const float*)d_in[14];
  const float* g3  = (const float*)d_in[15];
  const float* be3 = (const float*)d_in[16];
  const float* w5  = (const float*)d_in[17];
  const float* g5  = (const float*)d_in[18];
  const float* be5 = (const float*)d_in[19];
  const float* w7  = (const float*)d_in[20];
  const float* g7  = (const float*)d_in[21];
  const float* be7 = (const float*)d_in[22];
  const float* w1  = (const float*)d_in[23];
  const float* g1  = (const float*)d_in[24];
  const float* be1 = (const float*)d_in[25];
  const float* b1  = (const float*)d_in[26];

  char* ws = (char*)d_ws;
  bf16* concatA  = (bf16*)ws;                       // 67,108,864 B
  u8*   concatB  = (u8*)(ws + 67108864ULL);         // 33,554,432 B
  bf16* x3b      = (bf16*)(ws + 100663296ULL);
  bf16* x5b      = (bf16*)(ws + 134217728ULL);
  bf16* x7b      = (bf16*)(ws + 167772160ULL);
  bf16* x1b      = (bf16*)(ws + 201326592ULL);
  float* parts   = (float*)(ws + 234881024ULL);     // 4 * 2048 floats
  bf16* projchunk = (bf16*)(ws + 100663296ULL);     // overlaps x3..x1; dead before convs

  for (int g = 0; g < 2; ++g) {
    proj_chunk_kernel<<<dim3(8, 128), 256, 0, stream>>>(st, phy,
        wq_st, bq_st, wk_st, bk_st, wv_st, bv_st,
        wq_phy, bq_phy, wk_phy, bk_phy, wv_phy, bv_phy, projchunk, g * 64);
    attn_chunk_kernel<<<dim3(64, 128), 64, 0, stream>>>(projchunk, st, phy,
        concatA, concatB, g * 64);
  }
  conv_kernel<3><<<dim3(8, 128), 256, 0, stream>>>(concatA, concatB, w3, x3b, parts);
  conv_kernel<5><<<dim3(8, 128), 256, 0, stream>>>(concatA, concatB, w5, x5b, parts + 2048);
  conv_kernel<7><<<dim3(8, 128), 256, 0, stream>>>(concatA, concatB, w7, x7b, parts + 4096);
  conv1_kernel<<<dim3(8, 128), 256, 0, stream>>>(concatA, concatB, w1, b1, x1b, parts + 6144);
  final_kernel<<<dim3(8, 128), 256, 0, stream>>>(x3b, x5b, x7b, x1b,
      parts, parts + 2048, parts + 4096, parts + 6144,
      g3, be3, g5, be5, g7, be7, g1, be1, (float*)d_out);
}

// Round 3
// 3943.650 us; speedup vs baseline: 5.0315x; 5.0315x over previous
//
#include <hip/hip_runtime.h>
#include <hip/hip_bf16.h>

typedef __hip_bfloat16 bf16;
typedef unsigned char u8;
typedef __attribute__((ext_vector_type(8))) short short8;
typedef __attribute__((ext_vector_type(16))) float f32x16;
#define DI __device__ __forceinline__

union BF8 { int4 v; short8 s; bf16 h[8]; };
union BF4 { unsigned long long u; bf16 h[4]; };

// ---------------------------------------------------------------- ws layout (bytes)
// phase A (proj/attn):  projchunk bf16 [6][128][64][1024] @ 0           (100,663,296)
//                       cA bf16 [128][256][1024]          @ 100,663,296 ( 67,108,864)
//                       cB u8   [128][256][1024]          @ 167,772,160 ( 33,554,432)
// phase B (transpose):  cAT bf16 [128][1024 pos][256 ch]  @ 0           ( 67,108,864)
//                       cBT u8   [128][1024 pos][256 ch]  @ 67,108,864  ( 33,554,432)
// phase C (convs):      x3 @100,663,296  x5 @134,217,728  x7 @167,772,160  x1 @201,326,592
// parts f32             @ 234,881,024 (32 KB)
// wb3/wb5/wb7 bf16 [tap][128 oc][512 ic] @ 234,913,792 / 236,093,440 / 239,370,240
// w1T bf16 [128][512] @ 245,792,768   (end 245,923,840 < 256 MiB)

// ---------------------------------------------------------------- weight prep
__global__ __launch_bounds__(256) void prep_w_kernel(
    const float* __restrict__ w3, const float* __restrict__ w5,
    const float* __restrict__ w7, const float* __restrict__ w1,
    bf16* __restrict__ wb3, bf16* __restrict__ wb5,
    bf16* __restrict__ wb7, bf16* __restrict__ w1T)
{
  const int N3 = 9 * 65536, N5 = 25 * 65536, N7 = 49 * 65536, N1 = 65536;
  const int total = N3 + N5 + N7 + N1;
  for (int i = blockIdx.x * 256 + threadIdx.x; i < total; i += gridDim.x * 256) {
    if (i < N3) {
      int tap = i >> 16, rem = i & 65535;
      wb3[i] = __float2bfloat16(w3[(size_t)rem * 9 + tap]);
    } else if (i < N3 + N5) {
      int k = i - N3; int tap = k >> 16, rem = k & 65535;
      wb5[k] = __float2bfloat16(w5[(size_t)rem * 25 + tap]);
    } else if (i < N3 + N5 + N7) {
      int k = i - N3 - N5; int tap = k >> 16, rem = k & 65535;
      wb7[k] = __float2bfloat16(w7[(size_t)rem * 49 + tap]);
    } else {
      int k = i - N3 - N5 - N7;
      w1T[k] = __float2bfloat16(w1[k]);
    }
  }
}

// ---------------------------------------------------------------- projections (64-ch chunk)
__global__ __launch_bounds__(256) void proj_chunk_kernel(
    const float* __restrict__ st, const float* __restrict__ phy,
    const float* __restrict__ w0, const float* __restrict__ b0,
    const float* __restrict__ w1, const float* __restrict__ b1,
    const float* __restrict__ w2, const float* __restrict__ b2,
    const float* __restrict__ w3, const float* __restrict__ b3,
    const float* __restrict__ w4, const float* __restrict__ b4,
    const float* __restrict__ w5, const float* __restrict__ b5,
    bf16* __restrict__ pc, int cb)
{
  __shared__ __align__(16) bf16 Xs[128][128];
  __shared__ __align__(16) bf16 Ws[128][64];
  const int pt = blockIdx.x, b = blockIdx.y;
  const int tid = threadIdx.x;
  const int c0 = (tid >> 4) * 4;
  const int p0 = (tid & 15) * 8;

  #pragma unroll
  for (int mat = 0; mat < 6; ++mat) {
    const float* Wm; const float* Bm; const float* X;
    switch (mat) {
      case 0: Wm = w0; Bm = b0; X = st;  break;
      case 1: Wm = w1; Bm = b1; X = st;  break;
      case 2: Wm = w2; Bm = b2; X = st;  break;
      case 3: Wm = w3; Bm = b3; X = phy; break;
      case 4: Wm = w4; Bm = b4; X = phy; break;
      default:Wm = w5; Bm = b5; X = phy; break;
    }
    __syncthreads();
    if (mat == 0 || mat == 3) {
      for (int e = tid; e < 128 * 128; e += 256) {
        int i = e >> 7, p = e & 127;
        Xs[i][p] = __float2bfloat16(X[((size_t)b * 128 + i) * 1024 + pt * 128 + p]);
      }
    }
    for (int e = tid; e < 64 * 128; e += 256) {
      int c = e >> 7, i = e & 127;
      Ws[i][c] = __float2bfloat16(Wm[(cb + c) * 128 + i]);
    }
    __syncthreads();

    float acc[4][8];
    #pragma unroll
    for (int a = 0; a < 4; ++a)
      #pragma unroll
      for (int d = 0; d < 8; ++d) acc[a][d] = 0.f;

    #pragma unroll 2
    for (int i = 0; i < 128; ++i) {
      BF4 wv; wv.u = *(const unsigned long long*)&Ws[i][c0];
      BF8 xv; xv.v = *(const int4*)&Xs[i][p0];
      float wf[4], xf[8];
      #pragma unroll
      for (int j = 0; j < 4; ++j) wf[j] = __bfloat162float(wv.h[j]);
      #pragma unroll
      for (int j = 0; j < 8; ++j) xf[j] = __bfloat162float(xv.h[j]);
      #pragma unroll
      for (int cc = 0; cc < 4; ++cc)
        #pragma unroll
        for (int pp = 0; pp < 8; ++pp)
          acc[cc][pp] = fmaf(wf[cc], xf[pp], acc[cc][pp]);
    }
    #pragma unroll
    for (int cc = 0; cc < 4; ++cc) {
      float bias = Bm[cb + c0 + cc];
      BF8 pk;
      #pragma unroll
      for (int pp = 0; pp < 8; ++pp) pk.h[pp] = __float2bfloat16(acc[cc][pp] + bias);
      *(int4*)&pc[(((size_t)mat * 128 + b) * 64 + c0 + cc) * 1024 + pt * 128 + p0] = pk.v;
    }
  }
}

// ---------------------------------------------------------------- attention helpers
DI void mm32(const float* A, int sa, const float* Bm, int sb,
             float acc[4][4], int r0, int c0)
{
  #pragma unroll 4
  for (int w = 0; w < 32; ++w) {
    float qv[4], kv[4];
    *(float4*)qv = *(const float4*)(A + w * sa + r0);
    *(float4*)kv = *(const float4*)(Bm + w * sb + c0);
    #pragma unroll
    for (int i = 0; i < 4; ++i)
      #pragma unroll
      for (int j = 0; j < 4; ++j)
        acc[i][j] = fmaf(qv[i], kv[j], acc[i][j]);
  }
}

DI void softmax4(float acc[4][4])
{
  #pragma unroll
  for (int i = 0; i < 4; ++i) {
    float m = fmaxf(fmaxf(acc[i][0], acc[i][1]), fmaxf(acc[i][2], acc[i][3]));
    m = fmaxf(m, __shfl_xor(m, 1));
    m = fmaxf(m, __shfl_xor(m, 2));
    m = fmaxf(m, __shfl_xor(m, 4));
    float s = 0.f;
    #pragma unroll
    for (int j = 0; j < 4; ++j) { acc[i][j] = __expf(acc[i][j] - m); s += acc[i][j]; }
    s += __shfl_xor(s, 1); s += __shfl_xor(s, 2); s += __shfl_xor(s, 4);
    float rs = 1.0f / s;
    #pragma unroll
    for (int j = 0; j < 4; ++j) acc[i][j] *= rs;
  }
}

template<bool U8OUT>
DI void attn_one(const float* Qt, const float* K, const float* V, float (*At)[36],
                 const float* resid, void* outp, int r0, int c0)
{
  float acc[4][4] = {};
  mm32(Qt, 36, K, 32, acc, r0, c0);
  softmax4(acc);
  __syncthreads();
  #pragma unroll
  for (int j = 0; j < 4; ++j)
    *(float4*)&At[c0 + j][r0] = make_float4(acc[0][j], acc[1][j], acc[2][j], acc[3][j]);
  __syncthreads();
  float o[4][4] = {};
  mm32(&At[0][0], 36, V, 32, o, r0, c0);
  softmax4(o);
  if constexpr (!U8OUT) {
    bf16* op = (bf16*)outp;
    if (resid) {
      #pragma unroll
      for (int i = 0; i < 4; ++i) {
        float4 rv = *(const float4*)&resid[(r0 + i) * 32 + c0];
        o[i][0] += rv.x; o[i][1] += rv.y; o[i][2] += rv.z; o[i][3] += rv.w;
      }
    }
    #pragma unroll
    for (int i = 0; i < 4; ++i) {
      BF4 pk;
      #pragma unroll
      for (int j = 0; j < 4; ++j) pk.h[j] = __float2bfloat16(o[i][j]);
      *(unsigned long long*)&op[(r0 + i) * 32 + c0] = pk.u;
    }
  } else {
    u8* op = (u8*)outp;
    #pragma unroll
    for (int i = 0; i < 4; ++i) {
      unsigned pk = 0;
      #pragma unroll
      for (int j = 0; j < 4; ++j) {
        unsigned bv = (unsigned)fminf(o[i][j] * 256.f + 0.5f, 255.f);
        pk |= bv << (8 * j);
      }
      *(unsigned*)&op[(r0 + i) * 32 + c0] = pk;
    }
  }
}

// ---------------------------------------------------------------- attention (64-ch chunk)
__global__ __launch_bounds__(64) void attn_chunk_kernel(
    const bf16* __restrict__ pc,
    const float* __restrict__ st, const float* __restrict__ phy,
    bf16* __restrict__ cA, u8* __restrict__ cB, int cb)
{
  __shared__ __align__(16) float Qst[32][36], Qphy[32][36];
  __shared__ __align__(16) float Kst[32][32], Kphy[32][32];
  __shared__ __align__(16) float Vst[32][32], Vphy[32][32];
  __shared__ __align__(16) float At[32][36];
  const int cl = blockIdx.x, b = blockIdx.y;
  const int c = cb + cl;
  const int lane = threadIdx.x;
  const size_t mstride = (size_t)128 * 64 * 1024;
  const bf16* p0 = pc + ((size_t)b * 64 + cl) * 1024;
  const size_t bc = ((size_t)b * 128 + c) * 1024;

  for (int e = lane; e < 1024; e += 64) {
    int h = e >> 5, w = e & 31;
    Qst[w][h]  = __bfloat162float(p0[e]);
    Kst[h][w]  = __bfloat162float(p0[mstride + e]);
    Vst[h][w]  = __bfloat162float(p0[2 * mstride + e]);
    Qphy[w][h] = __bfloat162float(p0[3 * mstride + e]);
    Kphy[h][w] = __bfloat162float(p0[4 * mstride + e]);
    Vphy[h][w] = __bfloat162float(p0[5 * mstride + e]);
  }
  __syncthreads();
  const int r0 = (lane >> 3) * 4, c0 = (lane & 7) * 4;
  bf16* aA = cA + (size_t)b * 256 * 1024 + (size_t)c * 1024;
  u8*   aB = cB + (size_t)b * 256 * 1024 + (size_t)c * 1024;

  attn_one<false>(&Qst[0][0],  &Kst[0][0],  &Vst[0][0],  At, st + bc,  aA,               r0, c0);
  attn_one<false>(&Qphy[0][0], &Kphy[0][0], &Vphy[0][0], At, phy + bc, aA + 128 * 1024,  r0, c0);
  attn_one<true >(&Qphy[0][0], &Kst[0][0],  &Vst[0][0],  At, nullptr,  aB,               r0, c0);
  attn_one<true >(&Qst[0][0],  &Kphy[0][0], &Vphy[0][0], At, nullptr,  aB + 128 * 1024,  r0, c0);
}

// ---------------------------------------------------------------- concat transpose -> [b][pos][ch]
__global__ __launch_bounds__(256) void transpose_kernel(
    const bf16* __restrict__ cA, const u8* __restrict__ cB,
    bf16* __restrict__ cAT, u8* __restrict__ cBT)
{
  __shared__ __align__(16) short Tb[64 * 72];
  __shared__ __align__(16) u8 T8[64 * 80];
  const int x = blockIdx.x, b = blockIdx.y;
  const int cht = x >> 4, post = x & 15;
  const int pos0 = post * 64;
  const int tid = threadIdx.x;
  const int rowi = tid >> 2, sub = tid & 3;

  if (cht < 4) {
    const int ch0 = cht * 64;
    const bf16* src = cA + ((size_t)b * 256 + ch0 + rowi) * 1024 + pos0 + sub * 16;
    *(int4*)&Tb[rowi * 72 + sub * 16]     = *(const int4*)src;
    *(int4*)&Tb[rowi * 72 + sub * 16 + 8] = *(const int4*)(src + 8);
    __syncthreads();
    short tmp[16];
    #pragma unroll
    for (int j = 0; j < 16; ++j) tmp[j] = Tb[(sub * 16 + j) * 72 + rowi];
    bf16* dst = cAT + ((size_t)b * 1024 + pos0 + rowi) * 256 + ch0 + sub * 16;
    *(int4*)dst       = ((int4*)tmp)[0];
    *(int4*)(dst + 8) = ((int4*)tmp)[1];
  } else {
    const int ch0 = (cht - 4) * 64;
    const u8* src = cB + ((size_t)b * 256 + ch0 + rowi) * 1024 + pos0 + sub * 16;
    *(int4*)&T8[rowi * 80 + sub * 16] = *(const int4*)src;
    __syncthreads();
    u8 tmp[16];
    #pragma unroll
    for (int j = 0; j < 16; ++j) tmp[j] = T8[(sub * 16 + j) * 80 + rowi];
    u8* dst = cBT + ((size_t)b * 1024 + pos0 + rowi) * 256 + ch0 + sub * 16;
    *(int4*)dst = *(int4*)tmp;
  }
}

// ---------------------------------------------------------------- MFMA conv k=3/5/7
template<int KS>
__global__ __launch_bounds__(256) void conv_mfma(
    const bf16* __restrict__ cAT, const u8* __restrict__ cBT,
    const bf16* __restrict__ wt, bf16* __restrict__ xout,
    float* __restrict__ partials)
{
  constexpr int H0 = KS / 2;
  constexpr int PR = 8 + 2 * H0;
  constexpr int PC = 32 + 2 * H0;
  constexpr int PPOS = PR * PC;
  __shared__ __align__(16) short Xs[PPOS * 40];   // [ppos][32 ic + 8 pad]
  __shared__ float rs[256], rq[256];
  const int pt = blockIdx.x & 3, ot = blockIdx.x >> 2;
  const int b = blockIdx.y;
  const int r0 = pt * 8, oc0 = ot * 64;
  const int tid = threadIdx.x;
  const int wave = tid >> 6, lane = tid & 63;
  const int col = lane & 31, kg = lane >> 5;

  f32x16 acc[2][2];
  #pragma unroll
  for (int i = 0; i < 2; ++i)
    #pragma unroll
    for (int j = 0; j < 2; ++j)
      #pragma unroll
      for (int e = 0; e < 16; ++e) acc[i][j][e] = 0.f;

  const int base0 = ((2 * wave + 0) * PC + col) * 40 + kg * 8;
  const int base1 = ((2 * wave + 1) * PC + col) * 40 + kg * 8;

  for (int cc = 0; cc < 16; ++cc) {
    const int ic0 = cc * 32;
    __syncthreads();
    for (int g = tid; g < PPOS * 4; g += 256) {
      int ppos = g >> 2, part = g & 3;
      int prow = ppos / PC, pcol = ppos - prow * PC;
      int r = r0 + prow - H0, c = pcol - H0;
      int4 val = make_int4(0, 0, 0, 0);
      if ((unsigned)r < 32u && (unsigned)c < 32u) {
        size_t pbase = ((size_t)b * 1024 + r * 32 + c) * 256;
        if (ic0 < 256) {
          val = *(const int4*)&cAT[pbase + ic0 + part * 8];
        } else {
          const u8* s = &cBT[pbase + (ic0 - 256) + part * 8];
          unsigned lo = *(const unsigned*)s, hi = *(const unsigned*)(s + 4);
          BF8 t;
          #pragma unroll
          for (int j = 0; j < 4; ++j) t.h[j]     = __float2bfloat16((float)((lo >> (8 * j)) & 255u) * 0.00390625f);
          #pragma unroll
          for (int j = 0; j < 4; ++j) t.h[4 + j] = __float2bfloat16((float)((hi >> (8 * j)) & 255u) * 0.00390625f);
          val = t.v;
        }
      }
      *(int4*)&Xs[ppos * 40 + part * 8] = val;
    }
    __syncthreads();

    const bf16* wchunk = wt + ((size_t)(oc0 + col)) * 512 + ic0 + kg * 8;
    #pragma unroll
    for (int ky = 0; ky < KS; ++ky) {
      #pragma unroll
      for (int kx = 0; kx < KS; ++kx) {
        const int tap = ky * KS + kx;
        const int toff = (ky * PC + kx) * 40;
        BF8 a00, a01, a10, a11;
        a00.v = *(const int4*)&wchunk[((size_t)tap * 128 +  0) * 512 +  0];
        a01.v = *(const int4*)&wchunk[((size_t)tap * 128 +  0) * 512 + 16];
        a10.v = *(const int4*)&wchunk[((size_t)tap * 128 + 32) * 512 +  0];
        a11.v = *(const int4*)&wchunk[((size_t)tap * 128 + 32) * 512 + 16];
        short8 b00 = *(const short8*)&Xs[base0 + toff];
        short8 b01 = *(const short8*)&Xs[base0 + toff + 16];
        short8 b10 = *(const short8*)&Xs[base1 + toff];
        short8 b11 = *(const short8*)&Xs[base1 + toff + 16];
        acc[0][0] = __builtin_amdgcn_mfma_f32_32x32x16_bf16(a00.s, b00, acc[0][0], 0, 0, 0);
        acc[0][1] = __builtin_amdgcn_mfma_f32_32x32x16_bf16(a00.s, b10, acc[0][1], 0, 0, 0);
        acc[1][0] = __builtin_amdgcn_mfma_f32_32x32x16_bf16(a10.s, b00, acc[1][0], 0, 0, 0);
        acc[1][1] = __builtin_amdgcn_mfma_f32_32x32x16_bf16(a10.s, b10, acc[1][1], 0, 0, 0);
        acc[0][0] = __builtin_amdgcn_mfma_f32_32x32x16_bf16(a01.s, b01, acc[0][0], 0, 0, 0);
        acc[0][1] = __builtin_amdgcn_mfma_f32_32x32x16_bf16(a01.s, b11, acc[0][1], 0, 0, 0);
        acc[1][0] = __builtin_amdgcn_mfma_f32_32x32x16_bf16(a11.s, b01, acc[1][0], 0, 0, 0);
        acc[1][1] = __builtin_amdgcn_mfma_f32_32x32x16_bf16(a11.s, b11, acc[1][1], 0, 0, 0);
      }
    }
  }

  float lsum = 0.f, lsq = 0.f;
  #pragma unroll
  for (int mf = 0; mf < 2; ++mf)
    #pragma unroll
    for (int rr = 0; rr < 2; ++rr) {
      const int row = r0 + 2 * wave + rr;
      #pragma unroll
      for (int r = 0; r < 16; ++r) {
        const int oc = oc0 + mf * 32 + (r & 3) + 8 * (r >> 2) + 4 * kg;
        float v = acc[mf][rr][r];
        xout[((size_t)b * 128 + oc) * 1024 + row * 32 + col] = __float2bfloat16(v);
        lsum += v; lsq += v * v;
      }
    }
  rs[tid] = lsum; rq[tid] = lsq;
  __syncthreads();
  for (int s = 128; s > 0; s >>= 1) {
    if (tid < s) { rs[tid] += rs[tid + s]; rq[tid] += rq[tid + s]; }
    __syncthreads();
  }
  if (tid == 0) {
    partials[((size_t)b * 8 + blockIdx.x) * 2]     = rs[0];
    partials[((size_t)b * 8 + blockIdx.x) * 2 + 1] = rq[0];
  }
}

// ---------------------------------------------------------------- MFMA conv k=1 + b1
__global__ __launch_bounds__(256) void conv1_mfma(
    const bf16* __restrict__ cAT, const u8* __restrict__ cBT,
    const bf16* __restrict__ w1T, const float* __restrict__ b1,
    bf16* __restrict__ xout, float* __restrict__ partials)
{
  __shared__ float rs[256], rq[256];
  const int pt = blockIdx.x, b = blockIdx.y;
  const int tid = threadIdx.x, wave = tid >> 6, lane = tid & 63;
  const int col = lane & 31, kg = lane >> 5;
  const int pos = pt * 128 + wave * 32 + col;

  f32x16 acc[4];
  #pragma unroll
  for (int i = 0; i < 4; ++i)
    #pragma unroll
    for (int e = 0; e < 16; ++e) acc[i][e] = 0.f;

  const bf16* wbase = w1T + (size_t)col * 512 + kg * 8;
  const size_t pbase = ((size_t)b * 1024 + pos) * 256;

  #pragma unroll 2
  for (int kst = 0; kst < 32; ++kst) {
    short8 bfr;
    if (kst < 16) {
      bfr = *(const short8*)&cAT[pbase + kst * 16 + kg * 8];
    } else {
      const u8* s = &cBT[pbase + (kst - 16) * 16 + kg * 8];
      unsigned lo = *(const unsigned*)s, hi = *(const unsigned*)(s + 4);
      BF8 t;
      #pragma unroll
      for (int j = 0; j < 4; ++j) t.h[j]     = __float2bfloat16((float)((lo >> (8 * j)) & 255u) * 0.00390625f);
      #pragma unroll
      for (int j = 0; j < 4; ++j) t.h[4 + j] = __float2bfloat16((float)((hi >> (8 * j)) & 255u) * 0.00390625f);
      bfr = t.s;
    }
    #pragma unroll
    for (int mf = 0; mf < 4; ++mf) {
      BF8 a; a.v = *(const int4*)&wbase[((size_t)mf * 32) * 512 + kst * 16];
      acc[mf] = __builtin_amdgcn_mfma_f32_32x32x16_bf16(a.s, bfr, acc[mf], 0, 0, 0);
    }
  }

  float lsum = 0.f, lsq = 0.f;
  #pragma unroll
  for (int mf = 0; mf < 4; ++mf) {
    #pragma unroll
    for (int r = 0; r < 16; ++r) {
      const int oc = mf * 32 + (r & 3) + 8 * (r >> 2) + 4 * kg;
      float v = acc[mf][r] + b1[oc];
      xout[((size_t)b * 128 + oc) * 1024 + pos] = __float2bfloat16(v);
      lsum += v; lsq += v * v;
    }
  }
  rs[tid] = lsum; rq[tid] = lsq;
  __syncthreads();
  for (int s = 128; s > 0; s >>= 1) {
    if (tid < s) { rs[tid] += rs[tid + s]; rq[tid] += rq[tid + s]; }
    __syncthreads();
  }
  if (tid == 0) {
    partials[((size_t)b * 8 + pt) * 2]     = rs[0];
    partials[((size_t)b * 8 + pt) * 2 + 1] = rq[0];
  }
}

// ---------------------------------------------------------------- LN + combine
__global__ __launch_bounds__(256) void final_kernel(
    const bf16* __restrict__ x3, const bf16* __restrict__ x5,
    const bf16* __restrict__ x7, const bf16* __restrict__ x1c,
    const float* __restrict__ p3, const float* __restrict__ p5,
    const float* __restrict__ p7, const float* __restrict__ p1,
    const float* __restrict__ g3, const float* __restrict__ be3,
    const float* __restrict__ g5, const float* __restrict__ be5,
    const float* __restrict__ g7, const float* __restrict__ be7,
    const float* __restrict__ g1, const float* __restrict__ be1,
    float* __restrict__ out)
{
  const int blk = blockIdx.x, b = blockIdx.y, tid = threadIdx.x;
  float s3 = 0, q3 = 0, s5 = 0, q5 = 0, s7 = 0, q7 = 0, s1 = 0, q1 = 0;
  #pragma unroll
  for (int i = 0; i < 8; ++i) {
    int o = (b * 8 + i) * 2;
    s3 += p3[o]; q3 += p3[o + 1];
    s5 += p5[o]; q5 += p5[o + 1];
    s7 += p7[o]; q7 += p7[o + 1];
    s1 += p1[o]; q1 += p1[o + 1];
  }
  const float inv = 1.0f / 131072.0f;
  float mu3 = s3 * inv, r3 = rsqrtf(fmaxf(q3 * inv - mu3 * mu3, 0.f) + 1e-5f);
  float mu5 = s5 * inv, r5 = rsqrtf(fmaxf(q5 * inv - mu5 * mu5, 0.f) + 1e-5f);
  float mu7 = s7 * inv, r7 = rsqrtf(fmaxf(q7 * inv - mu7 * mu7, 0.f) + 1e-5f);
  float mu1 = s1 * inv, r1 = rsqrtf(fmaxf(q1 * inv - mu1 * mu1, 0.f) + 1e-5f);
  const size_t bb = (size_t)b * 131072;
  for (int it = 0; it < 8; ++it) {
    int e0 = (it * 2048 + blk * 256 + tid) * 8;
    BF8 a3, a5, a7, a1;
    a3.v = *(const int4*)&x3[bb + e0];
    a5.v = *(const int4*)&x5[bb + e0];
    a7.v = *(const int4*)&x7[bb + e0];
    a1.v = *(const int4*)&x1c[bb + e0];
    float G3[8], B3[8], G5[8], B5[8], G7[8], B7[8], G1[8], B1[8];
    *(float4*)&G3[0] = *(const float4*)&g3[e0];  *(float4*)&G3[4] = *(const float4*)&g3[e0 + 4];
    *(float4*)&B3[0] = *(const float4*)&be3[e0]; *(float4*)&B3[4] = *(const float4*)&be3[e0 + 4];
    *(float4*)&G5[0] = *(const float4*)&g5[e0];  *(float4*)&G5[4] = *(const float4*)&g5[e0 + 4];
    *(float4*)&B5[0] = *(const float4*)&be5[e0]; *(float4*)&B5[4] = *(const float4*)&be5[e0 + 4];
    *(float4*)&G7[0] = *(const float4*)&g7[e0];  *(float4*)&G7[4] = *(const float4*)&g7[e0 + 4];
    *(float4*)&B7[0] = *(const float4*)&be7[e0]; *(float4*)&B7[4] = *(const float4*)&be7[e0 + 4];
    *(float4*)&G1[0] = *(const float4*)&g1[e0];  *(float4*)&G1[4] = *(const float4*)&g1[e0 + 4];
    *(float4*)&B1[0] = *(const float4*)&be1[e0]; *(float4*)&B1[4] = *(const float4*)&be1[e0 + 4];
    float res[8];
    #pragma unroll
    for (int j = 0; j < 8; ++j) {
      float v3 = (__bfloat162float(a3.h[j]) - mu3) * r3 * G3[j] + B3[j];
      float v5 = (__bfloat162float(a5.h[j]) - mu5) * r5 * G5[j] + B5[j];
      float v7 = (__bfloat162float(a7.h[j]) - mu7) * r7 * G7[j] + B7[j];
      float m = (v3 + v5 + v7) * (1.0f / 3.0f);
      float sg = 1.0f / (1.0f + __expf(-m));
      float v1 = (__bfloat162float(a1.h[j]) - mu1) * r1 * G1[j] + B1[j];
      res[j] = sg + v1;
    }
    *(float4*)&out[bb + e0]     = make_float4(res[0], res[1], res[2], res[3]);
    *(float4*)&out[bb + e0 + 4] = make_float4(res[4], res[5], res[6], res[7]);
  }
}

// ---------------------------------------------------------------- launch
extern "C" void kernel_launch(void* const* d_in, const int* in_sizes, int n_in,
                              void* d_out, int out_size, void* d_ws, size_t ws_size,
                              hipStream_t stream)
{
  (void)in_sizes; (void)n_in; (void)out_size; (void)ws_size;
  const float* st     = (const float*)d_in[0];
  const float* phy    = (const float*)d_in[1];
  const float* wq_st  = (const float*)d_in[2];
  const float* bq_st  = (const float*)d_in[3];
  const float* wk_st  = (const float*)d_in[4];
  const float* bk_st  = (const float*)d_in[5];
  const float* wv_st  = (const float*)d_in[6];
  const float* bv_st  = (const float*)d_in[7];
  const float* wq_phy = (const float*)d_in[8];
  const float* bq_phy = (const float*)d_in[9];
  const float* wk_phy = (const float*)d_in[10];
  const float* bk_phy = (const float*)d_in[11];
  const float* wv_phy = (const float*)d_in[12];
  const float* bv_phy = (const float*)d_in[13];
  const float* w3  = (const float*)d_in[14];
  const float* g3  = (const float*)d_in[15];
  const float* be3 = (const float*)d_in[16];
  const float* w5  = (const float*)d_in[17];
  const float* g5  = (const float*)d_in[18];
  const float* be5 = (const float*)d_in[19];
  const float* w7  = (const float*)d_in[20];
  const float* g7  = (const float*)d_in[21];
  const float* be7 = (const float*)d_in[22];
  const float* w1  = (const float*)d_in[23];
  const float* g1  = (const float*)d_in[24];
  const float* be1 = (const float*)d_in[25];
  const float* b1  = (const float*)d_in[26];

  char* ws = (char*)d_ws;
  bf16* cAT      = (bf16*)ws;
  u8*   cBT      = (u8*)(ws + 67108864ULL);
  bf16* projchunk = (bf16*)ws;                      // phase A only
  bf16* cA       = (bf16*)(ws + 100663296ULL);      // phase A only
  u8*   cB       = (u8*)(ws + 167772160ULL);        // phase A only
  bf16* x3b      = (bf16*)(ws + 100663296ULL);
  bf16* x5b      = (bf16*)(ws + 134217728ULL);
  bf16* x7b      = (bf16*)(ws + 167772160ULL);
  bf16* x1b      = (bf16*)(ws + 201326592ULL);
  float* parts   = (float*)(ws + 234881024ULL);
  bf16* wb3      = (bf16*)(ws + 234913792ULL);
  bf16* wb5      = (bf16*)(ws + 236093440ULL);
  bf16* wb7      = (bf16*)(ws + 239370240ULL);
  bf16* w1T      = (bf16*)(ws + 245792768ULL);

  prep_w_kernel<<<dim3(2048), 256, 0, stream>>>(w3, w5, w7, w1, wb3, wb5, wb7, w1T);

  for (int g = 0; g < 2; ++g) {
    proj_chunk_kernel<<<dim3(8, 128), 256, 0, stream>>>(st, phy,
        wq_st, bq_st, wk_st, bk_st, wv_st, bv_st,
        wq_phy, bq_phy, wk_phy, bk_phy, wv_phy, bv_phy, projchunk, g * 64);
    attn_chunk_kernel<<<dim3(64, 128), 64, 0, stream>>>(projchunk, st, phy,
        cA, cB, g * 64);
  }
  transpose_kernel<<<dim3(128, 128), 256, 0, stream>>>(cA, cB, cAT, cBT);

  conv_mfma<3><<<dim3(8, 128), 256, 0, stream>>>(cAT, cBT, wb3, x3b, parts);
  conv_mfma<5><<<dim3(8, 128), 256, 0, stream>>>(cAT, cBT, wb5, x5b, parts + 2048);
  conv_mfma<7><<<dim3(8, 128), 256, 0, stream>>>(cAT, cBT, wb7, x7b, parts + 4096);
  conv1_mfma<<<dim3(8, 128), 256, 0, stream>>>(cAT, cBT, w1T, b1, x1b, parts + 6144);

  final_kernel<<<dim3(8, 128), 256, 0, stream>>>(x3b, x5b, x7b, x1b,
      parts, parts + 2048, parts + 4096, parts + 6144,
      g3, be3, g5, be5, g7, be7, g1, be1, (float*)d_out);
}